// Round 10
// baseline (703.619 us; speedup 1.0000x reference)
//
#include <hip/hip_runtime.h>
#include <math.h>

#define BB 8
#define NN 768
#define TT 769
#define DD 256
#define HH 8
#define DKK 32
#define FF 128
#define LL 6
#define MM 6152              // BB*TT
#define SCALE 0.17677669529663687f   // 1/sqrt(32)
#define TP 832               // vt row pitch (keys padded)
#define KQP 784              // q/k head-major row count (padded)
#define KHS (KQP * DKK)      // shorts per head slice (25088)
#define GBP 776              // bias global pitch (ushort)
#define HP 264               // LDS row pitch (shorts) for 16x256 tiles
#define WSZ 65536            // shorts per swizzled weight matrix
#define NPK ((size_t)BB * 49 * 13 * 1024)   // packed bias elements

typedef __attribute__((ext_vector_type(8))) short s16x8;
typedef __attribute__((ext_vector_type(8))) unsigned short u16x8;
typedef __attribute__((ext_vector_type(4))) float f32x4;

__device__ inline short f2bf(float x) {
    unsigned u = __float_as_uint(x);
    unsigned r = (u + 0x7FFFu + ((u >> 16) & 1u)) >> 16;   // RNE
    return (short)r;
}
__device__ inline float bf2f(unsigned short s) {
    return __uint_as_float(((unsigned)s) << 16);
}
__device__ inline float gelu_f(float x) {
    return 0.5f * x * (1.f + erff(x * 0.70710678118654752f));
}

// ---------------- degree ----------------
__global__ __launch_bounds__(256) void deg_kernel(const int* __restrict__ adj,
                                                  float* __restrict__ deg) {
    int row  = blockIdx.x * 4 + (threadIdx.x >> 6);
    int lane = threadIdx.x & 63;
    const int* p = adj + (size_t)row * NN;
    int s = 0;
#pragma unroll
    for (int i = 0; i < NN / 64; ++i) s += p[lane + 64 * i];
#pragma unroll
    for (int off = 32; off > 0; off >>= 1) s += __shfl_xor(s, off);
    if (lane == 0) deg[row] = (float)s;
}

__global__ __launch_bounds__(256) void degmax_kernel(const float* __restrict__ deg,
                                                     float* __restrict__ dmax) {
    __shared__ float red[256];
    int b = blockIdx.x, t = threadIdx.x;
    float m = 0.f;
    for (int i = t; i < NN; i += 256) m = fmaxf(m, deg[b * NN + i]);
    red[t] = m;
    __syncthreads();
    for (int s = 128; s > 0; s >>= 1) {
        if (t < s) red[t] = fmaxf(red[t], red[t + s]);
        __syncthreads();
    }
    if (t == 0) dmax[b] = red[0];
}

// ---------------- attention bias (B,TT,GBP) bf16 ----------------
__global__ __launch_bounds__(256) void bias_kernel(
    const float* __restrict__ dist, const float* __restrict__ eoh,
    const int* __restrict__ adj, const float* __restrict__ deg,
    const float* __restrict__ dmax, const float* __restrict__ etw,
    const float* __restrict__ noedge, const float* __restrict__ degsc,
    const float* __restrict__ gamma, const float* __restrict__ v2n,
    const float* __restrict__ n2v, const float* __restrict__ vself,
    unsigned short* __restrict__ bias)
{
    long long idx = (long long)blockIdx.x * 256 + threadIdx.x;
    const long long total = (long long)BB * TT * GBP;
    if (idx >= total) return;
    int b  = (int)(idx / ((long long)TT * GBP));
    int r  = (int)(idx % ((long long)TT * GBP));
    int qi = r / GBP, kj = r % GBP;
    float out;
    if (kj >= TT)                out = 0.f;
    else if (qi == 0 && kj == 0) out = vself[0];
    else if (qi == 0)            out = v2n[0];
    else if (kj == 0)            out = n2v[0];
    else {
        int i = qi - 1, j = kj - 1;
        size_t e = ((size_t)b * NN + i) * NN + j;
        float4 oh = *(const float4*)(eoh + 4 * e);
        float val = oh.x * etw[0] + oh.y * etw[1] + oh.z * etw[2] + oh.w * etw[3]
                    - gamma[0] * dist[e];
        if (adj[e] == 0) val += noedge[0];
        val += degsc[0] * (deg[b * NN + i] + deg[b * NN + j]) / (dmax[b] + 1e-6f);
        out = val;
    }
    bias[idx] = (unsigned short)f2bf(out);
}

// ---------------- bias repack: per-(qtile,chunk,lane) packed layout -----------------
__global__ __launch_bounds__(256) void biaspk_kernel(
    const unsigned short* __restrict__ bias, unsigned short* __restrict__ bpk)
{
    int idx = blockIdx.x * 256 + threadIdx.x;
    int jj   = idx & 7;
    int lane = (idx >> 3) & 63;
    int half = (idx >> 9) & 1;
    int c    = (idx >> 10) % 13;
    int qtb  = idx / (13 * 1024);
    int b = qtb / 49, qt = qtb - b * 49;
    int quad = lane >> 4, m16 = lane & 15;
    int j = half * 8 + jj, s = j >> 2, r = j & 3;
    int kj = c * 64 + s * 16 + m16; if (kj >= TT) kj = 0;
    int qi = qt * 16 + quad * 4 + r; if (qi >= TT) qi = TT - 1;
    bpk[idx] = bias[(size_t)(b * TT + qi) * GBP + kj];
}

// ---------------- node projection + cls + LN1(layer0) ----------------
__global__ __launch_bounds__(256) void nodeproj_ln_kernel(
    const float* __restrict__ nf, const float* __restrict__ w,
    const float* __restrict__ bsv, const float* __restrict__ cls,
    const float* __restrict__ g, const float* __restrict__ bvec,
    float* __restrict__ x, short* __restrict__ xn)
{
    __shared__ float sf[FF];
    __shared__ float red[256];
    int row = blockIdx.x, t = threadIdx.x;
    int b = row / TT, tr = row % TT;
    float y;
    if (tr == 0) {
        y = cls[t];
    } else {
        if (t < FF) sf[t] = nf[((size_t)b * NN + tr - 1) * FF + t];
        __syncthreads();
        y = bsv[t];
#pragma unroll 8
        for (int kk = 0; kk < FF; ++kk) y = fmaf(sf[kk], w[kk * DD + t], y);
    }
    x[(size_t)row * DD + t] = y;
    red[t] = y;
    __syncthreads();
    for (int s = 128; s > 0; s >>= 1) { if (t < s) red[t] += red[t + s]; __syncthreads(); }
    float mean = red[0] * (1.f / DD);
    __syncthreads();
    float d = y - mean;
    red[t] = d * d;
    __syncthreads();
    for (int s = 128; s > 0; s >>= 1) { if (t < s) red[t] += red[t + s]; __syncthreads(); }
    float var = red[0] * (1.f / DD);
    xn[(size_t)row * DD + t] = f2bf(d * rsqrtf(var + 1e-5f) * g[t] + bvec[t]);
}

// ---------------- weight swizzle: W[k][n] f32 -> frag-major bf16 ----------------
__global__ __launch_bounds__(256) void wtrans_kernel(
    const float* __restrict__ qw, const float* __restrict__ kw,
    const float* __restrict__ vw, const float* __restrict__ ow,
    const float* __restrict__ f1w, const float* __restrict__ f2w,
    short* __restrict__ wt2)
{
    int mi = blockIdx.x >> 4, kg = blockIdx.x & 15;
    int fam = mi / 6, l = mi % 6;
    const float* W;
    if      (fam == 0) W = qw;
    else if (fam == 1) W = kw;
    else if (fam == 2) W = vw;
    else if (fam == 3) W = ow;
    else if (fam == 4) W = f1w;
    else               W = f2w;
    W += (size_t)l * DD * DD;
    int n = threadIdx.x;
    short* out = wt2 + (size_t)mi * WSZ;
#pragma unroll
    for (int kk = 0; kk < 16; ++kk) {
        int k = kg * 16 + kk;
        float val = W[(size_t)k * DD + n];
        size_t idx = (size_t)(((n >> 4) * 8 + (k >> 5)) * 512
                   + (((k >> 3) & 3) * 16 + (n & 15)) * 8 + (k & 7));
        out[idx] = f2bf(val);
    }
}

// ---------------- fused QKV GEMM (layer 0 only): 16 rows/block, 4 waves col-split ---
__global__ __launch_bounds__(256) void gemm_qkv_kernel(
    const short* __restrict__ A, const short* __restrict__ wtl,
    const float* __restrict__ qb, const float* __restrict__ kb,
    const float* __restrict__ vb,
    short* __restrict__ qh, short* __restrict__ kh, short* __restrict__ vtb)
{
    int t = threadIdx.x;
    int w = t >> 6, lane = t & 63, quad = lane >> 4, m16 = lane & 15;
    int m0 = blockIdx.x * 16;
    int fam = blockIdx.y;
    const short* Wf = wtl + (size_t)fam * 6 * WSZ;
    const float* bsv = fam == 0 ? qb : (fam == 1 ? kb : vb);
    int arow = m0 + m16; if (arow >= MM) arow = MM - 1;
    const short* ap = A + (size_t)arow * DD + quad * 8;
    const short* wbase = Wf + (size_t)(w * 4) * 4096 + lane * 8;
    f32x4 acc[4] = {};
#pragma unroll
    for (int kc = 0; kc < 8; ++kc) {
        s16x8 af = *(const s16x8*)(ap + kc * 32);
#pragma unroll
        for (int nt = 0; nt < 4; ++nt) {
            s16x8 bf = *(const s16x8*)(wbase + (size_t)nt * 4096 + kc * 512);
            acc[nt] = __builtin_amdgcn_mfma_f32_16x16x32_bf16(af, bf, acc[nt], 0, 0, 0);
        }
    }
    if (fam < 2) {
        short* outp = fam == 0 ? qh : kh;
#pragma unroll
        for (int r = 0; r < 4; ++r) {
            int row = m0 + quad * 4 + r;
            if (row < MM) {
                int b = row / TT;
                int tpos = row - b * TT;
                size_t rb = ((size_t)b * HH * KQP + tpos) * DKK;
#pragma unroll
                for (int nt = 0; nt < 4; ++nt) {
                    int col = w * 64 + nt * 16 + m16;
                    float bv = bsv[col];
                    int h = col >> 5, dk = col & 31;
                    outp[rb + (size_t)h * KHS + dk] = f2bf(acc[nt][r] + bv);
                }
            }
        }
    } else {
#pragma unroll
        for (int nt = 0; nt < 4; ++nt) {
            int col = w * 64 + nt * 16 + m16;
            float bv = bsv[col];
            int h = col >> 5, dk = col & 31;
#pragma unroll
            for (int r = 0; r < 4; ++r) {
                int row = m0 + quad * 4 + r;
                if (row < MM) {
                    int b = row / TT;
                    int tpos = row - b * TT;
                    vtb[(((size_t)(b * HH + h)) * DKK + dk) * TP + tpos] =
                        f2bf(acc[nt][r] + bv);
                }
            }
        }
    }
}

// ---------------- MEGA: attn + O-proj + LN2 + MLP + LN1next + QKV(l+1) --------------
// grid (392); block 512 = 8 waves = 8 heads; 16 q-rows per block.
// XCD mapping: b = bx & 7, qt = bx >> 3 -> under round-robin dispatch all 49
// q-tiles of batch b land on XCD b; per-XCD L2 working set (K/Q/V of one batch
// + bias slices + weights) ~= 4.8MB ~= L2 size, so K/V re-reads become L2 hits.
// Phase 3 (donext): the next layer's xn rows (already in registers) are staged
// to the dead xa tile and 3 GEMMs produce Q/K/V(l+1) into the PONG buffers --
// eliminates 5 of 6 gemm_qkv dispatches and the xn global round-trip.
__global__ __launch_bounds__(512) void mega_kernel(
    const short* __restrict__ q, const short* __restrict__ k,
    const short* __restrict__ vt, const unsigned short* __restrict__ bpk,
    const short* __restrict__ Wo, const short* __restrict__ W1,
    const short* __restrict__ W2,
    const float* __restrict__ ob, const float* __restrict__ g2,
    const float* __restrict__ b2, const float* __restrict__ f1b,
    const float* __restrict__ f2b, float* __restrict__ x,
    const float* __restrict__ g1, const float* __restrict__ b1,
    const short* __restrict__ Wq, const short* __restrict__ Wk,
    const short* __restrict__ Wv,
    const float* __restrict__ qbv, const float* __restrict__ kbv,
    const float* __restrict__ vbv,
    short* __restrict__ qho, short* __restrict__ kho,
    short* __restrict__ vto, int donext)
{
    __shared__ short Pb[8][16][72];        // 18.4KB per-wave P buffers
    __shared__ short xa[16][HP];           // 8.4KB attn-out tile / xn(l+1) stage
    __shared__ short xnl[16][HP];          // 8.4KB LN2-out tile
    __shared__ short hb[16][HP];           // 8.4KB gelu hidden tile
    __shared__ float redS[16][8], redQ[16][8];

    int t = threadIdx.x;
    int w = t >> 6, lane = t & 63;
    int quad = lane >> 4, m16 = lane & 15;
    int bx = blockIdx.x;
    int b = bx & 7;            // XCD-pinned batch
    int qt = bx >> 3;          // q-tile 0..48
    int h = w;
    int q0 = qt * 16;
    size_t qtb13 = (size_t)(b * 49 + qt) * 13;

    int qrow = q0 + m16;
    int qc = qrow < TT ? qrow : TT - 1;
    const short* qbase = q + (size_t)(b * HH + h) * KHS;
    s16x8 qa = *(const s16x8*)(qbase + (size_t)qc * DKK + quad * 8);

    const short* kbase = k + (size_t)(b * HH + h) * KHS;
    const short* vbase = vt + (((size_t)(b * HH + h)) * DKK) * TP;

    s16x8 kfA[4], kfB[4], vfA[4], vfB[4];
    u16x8 bbA0, bbA1, bbB0, bbB1;
    f32x4 sacc[4];
    f32x4 o0 = {0.f, 0.f, 0.f, 0.f};
    f32x4 o1 = {0.f, 0.f, 0.f, 0.f};
    float ls[4] = {0.f, 0.f, 0.f, 0.f};

#define LOADK_(DST, CC)                                                         \
    {                                                                           \
        _Pragma("unroll") for (int s = 0; s < 4; ++s) {                         \
            int kr = (CC) * 64 + s * 16 + m16;                                  \
            int kcl = kr < TT ? kr : TT - 1;                                    \
            DST[s] = *(const s16x8*)(kbase + (size_t)kcl * DKK + quad * 8);     \
        }                                                                       \
    }
#define LOADV_(DST, CC)                                                         \
    {                                                                           \
        int jn = (CC) * 64;                                                     \
        DST[0] = *(const s16x8*)(vbase + (size_t)m16 * TP + jn + quad * 8);     \
        DST[1] = *(const s16x8*)(vbase + (size_t)m16 * TP + jn + 32 + quad * 8);\
        DST[2] = *(const s16x8*)(vbase + (size_t)(16 + m16) * TP + jn + quad * 8);\
        DST[3] = *(const s16x8*)(vbase + (size_t)(16 + m16) * TP + jn + 32 + quad * 8);\
    }
#define LOADB_(D0, D1, CC)                                                      \
    {                                                                           \
        const unsigned short* bp_ = bpk + ((qtb13 + (CC)) << 10);               \
        D0 = *(const u16x8*)(bp_ + (lane << 3));                                \
        D1 = *(const u16x8*)(bp_ + 512 + (lane << 3));                         \
    }
#define STEP_(C, KPRE, KUSE, VUSE, VPRE, BU0, BU1, BP0, BP1, PK, PV, PBF, DOQK) \
    {                                                                           \
        if (PK)  LOADK_(KPRE, (C) + 2);                                         \
        if (PV)  LOADV_(VPRE, (C) + 1);                                         \
        if (PBF) LOADB_(BP0, BP1, (C) + 1);                                     \
        int j0 = (C) * 64;                                                      \
        _Pragma("unroll") for (int s = 0; s < 4; ++s) {                         \
            int key = j0 + s * 16 + m16;                                        \
            int kv = key < TT;                                                  \
            _Pragma("unroll") for (int r = 0; r < 4; ++r) {                     \
                int j = s * 4 + r;                                              \
                float bv = bf2f(j < 8 ? (unsigned short)BU0[j]                  \
                                      : (unsigned short)BU1[j - 8]);            \
                float sval = kv ? fmaf(sacc[s][r], SCALE, bv) : -1e30f;         \
                float p = __expf(sval - 8.0f);                                  \
                ls[r] += p;                                                     \
                Pb[w][quad * 4 + r][s * 16 + m16] = f2bf(p);                    \
            }                                                                   \
        }                                                                       \
        if (DOQK) {                                                             \
            f32x4 z = {0.f, 0.f, 0.f, 0.f};                                     \
            _Pragma("unroll") for (int s = 0; s < 4; ++s)                       \
                sacc[s] = __builtin_amdgcn_mfma_f32_16x16x32_bf16(qa, KUSE[s], z, 0, 0, 0); \
        }                                                                       \
        s16x8 pa0 = *(const s16x8*)&Pb[w][m16][quad * 8];                       \
        s16x8 pa1 = *(const s16x8*)&Pb[w][m16][32 + quad * 8];                  \
        o0 = __builtin_amdgcn_mfma_f32_16x16x32_bf16(pa0, VUSE[0], o0, 0, 0, 0);\
        o0 = __builtin_amdgcn_mfma_f32_16x16x32_bf16(pa1, VUSE[1], o0, 0, 0, 0);\
        o1 = __builtin_amdgcn_mfma_f32_16x16x32_bf16(pa0, VUSE[2], o1, 0, 0, 0);\
        o1 = __builtin_amdgcn_mfma_f32_16x16x32_bf16(pa1, VUSE[3], o1, 0, 0, 0);\
    }

    // prologue
    LOADK_(kfA, 0);
    LOADK_(kfB, 1);
    LOADV_(vfA, 0);
    LOADB_(bbA0, bbA1, 0);
    {
        f32x4 z = {0.f, 0.f, 0.f, 0.f};
#pragma unroll
        for (int s = 0; s < 4; ++s)
            sacc[s] = __builtin_amdgcn_mfma_f32_16x16x32_bf16(qa, kfA[s], z, 0, 0, 0);
    }

    // steady state: c = 0..9, rolled 2 steps per iteration (small hot loop)
    for (int cc = 0; cc < 5; ++cc) {
        STEP_(2 * cc,     kfA, kfB, vfA, vfB, bbA0, bbA1, bbB0, bbB1, 1, 1, 1, 1)
        STEP_(2 * cc + 1, kfB, kfA, vfB, vfA, bbB0, bbB1, bbA0, bbA1, 1, 1, 1, 1)
    }
    STEP_(10, kfA, kfB, vfA, vfB, bbA0, bbA1, bbB0, bbB1, 1, 1, 1, 1)
    STEP_(11, kfB, kfA, vfB, vfA, bbB0, bbB1, bbA0, bbA1, 0, 1, 1, 1)
    STEP_(12, kfA, kfB, vfA, vfB, bbA0, bbA1, bbB0, bbB1, 0, 0, 0, 0)

#undef STEP_
#undef LOADB_
#undef LOADV_
#undef LOADK_

    // attn epilogue -> LDS xa
#pragma unroll
    for (int r = 0; r < 4; ++r) {
        float l = ls[r];
#pragma unroll
        for (int off = 1; off < 16; off <<= 1) l += __shfl_xor(l, off);
        float inv = 1.f / l;
        int rl = quad * 4 + r;
        xa[rl][h * DKK + m16]      = f2bf(o0[r] * inv);
        xa[rl][h * DKK + 16 + m16] = f2bf(o1[r] * inv);
    }
    __syncthreads();   // (1) xa complete

    // ---------------- phase 2: O-proj + resid(reg) + LN2 ----------------
    const short* wob = Wo + (size_t)(w * 2) * 4096 + lane * 8;
    f32x4 acco[2] = {};
#pragma unroll
    for (int kc = 0; kc < 8; ++kc) {
        s16x8 af = *(const s16x8*)&xa[m16][kc * 32 + quad * 8];
#pragma unroll
        for (int ntl = 0; ntl < 2; ++ntl) {
            s16x8 bf = *(const s16x8*)(wob + (size_t)ntl * 4096 + kc * 512);
            acco[ntl] = __builtin_amdgcn_mfma_f32_16x16x32_bf16(af, bf, acco[ntl], 0, 0, 0);
        }
    }
    float vv[2][4], sr[4], q2[4];
#pragma unroll
    for (int r = 0; r < 4; ++r) { sr[r] = 0.f; q2[r] = 0.f; }
#pragma unroll
    for (int ntl = 0; ntl < 2; ++ntl) {
        int col = w * 32 + ntl * 16 + m16;
        float bv = ob[col];
#pragma unroll
        for (int r = 0; r < 4; ++r) {
            int row = q0 + quad * 4 + r; if (row >= TT) row = TT - 1;
            float v = acco[ntl][r] + bv + x[((size_t)(b * TT + row)) * DD + col];
            vv[ntl][r] = v; sr[r] += v; q2[r] += v * v;
        }
    }
#pragma unroll
    for (int r = 0; r < 4; ++r)
#pragma unroll
        for (int off = 1; off < 16; off <<= 1) {
            sr[r] += __shfl_xor(sr[r], off);
            q2[r] += __shfl_xor(q2[r], off);
        }
    if (m16 == 0) {
#pragma unroll
        for (int r = 0; r < 4; ++r) {
            redS[quad * 4 + r][w] = sr[r];
            redQ[quad * 4 + r][w] = q2[r];
        }
    }
    __syncthreads();   // (2) LN2 partials ready

#pragma unroll
    for (int r = 0; r < 4; ++r) {
        int rl = quad * 4 + r;
        float fs = 0.f, fq = 0.f;
#pragma unroll
        for (int j = 0; j < 8; ++j) { fs += redS[rl][j]; fq += redQ[rl][j]; }
        float mean = fs * (1.f / DD);
        float var = fq * (1.f / DD) - mean * mean;
        float inv = rsqrtf(var + 1e-5f);
#pragma unroll
        for (int ntl = 0; ntl < 2; ++ntl) {
            int col = w * 32 + ntl * 16 + m16;
            xnl[rl][col] = f2bf((vv[ntl][r] - mean) * inv * g2[col] + b2[col]);
        }
    }
    __syncthreads();   // (3) xnl complete

    // ---------------- FC1 + GELU -> hb ----------------
    const short* w1b = W1 + (size_t)(w * 2) * 4096 + lane * 8;
    f32x4 acc1[2] = {};
#pragma unroll
    for (int kc = 0; kc < 8; ++kc) {
        s16x8 af = *(const s16x8*)&xnl[m16][kc * 32 + quad * 8];
#pragma unroll
        for (int ntl = 0; ntl < 2; ++ntl) {
            s16x8 bf = *(const s16x8*)(w1b + (size_t)ntl * 4096 + kc * 512);
            acc1[ntl] = __builtin_amdgcn_mfma_f32_16x16x32_bf16(af, bf, acc1[ntl], 0, 0, 0);
        }
    }
#pragma unroll
    for (int ntl = 0; ntl < 2; ++ntl) {
        int col = w * 32 + ntl * 16 + m16;
        float fb = f1b[col];
#pragma unroll
        for (int r = 0; r < 4; ++r)
            hb[quad * 4 + r][col] = f2bf(gelu_f(acc1[ntl][r] + fb));
    }
    __syncthreads();   // (4) hidden complete

    // ---------------- FC2 + reg-resid + LN1next ----------------
    const short* w2b = W2 + (size_t)(w * 2) * 4096 + lane * 8;
    f32x4 acc2[2] = {};
#pragma unroll
    for (int kc = 0; kc < 8; ++kc) {
        s16x8 af = *(const s16x8*)&hb[m16][kc * 32 + quad * 8];
#pragma unroll
        for (int ntl = 0; ntl < 2; ++ntl) {
            s16x8 bf = *(const s16x8*)(w2b + (size_t)ntl * 4096 + kc * 512);
            acc2[ntl] = __builtin_amdgcn_mfma_f32_16x16x32_bf16(af, bf, acc2[ntl], 0, 0, 0);
        }
    }
#pragma unroll
    for (int r = 0; r < 4; ++r) { sr[r] = 0.f; q2[r] = 0.f; }
#pragma unroll
    for (int ntl = 0; ntl < 2; ++ntl) {
        int col = w * 32 + ntl * 16 + m16;
        float bv = f2b[col];
#pragma unroll
        for (int r = 0; r < 4; ++r) {
            float v = acc2[ntl][r] + bv + vv[ntl][r];   // resid = post-attn x (regs)
            vv[ntl][r] = v; sr[r] += v; q2[r] += v * v;
        }
    }
#pragma unroll
    for (int r = 0; r < 4; ++r)
#pragma unroll
        for (int off = 1; off < 16; off <<= 1) {
            sr[r] += __shfl_xor(sr[r], off);
            q2[r] += __shfl_xor(q2[r], off);
        }
    if (m16 == 0) {
#pragma unroll
        for (int r = 0; r < 4; ++r) {
            redS[quad * 4 + r][w] = sr[r];
            redQ[quad * 4 + r][w] = q2[r];
        }
    }
    __syncthreads();   // (5) LN1 partials ready

#pragma unroll
    for (int r = 0; r < 4; ++r) {
        int rl = quad * 4 + r;
        int row = q0 + rl;
        float fs = 0.f, fq = 0.f;
#pragma unroll
        for (int j = 0; j < 8; ++j) { fs += redS[rl][j]; fq += redQ[rl][j]; }
        float mean = fs * (1.f / DD);
        float var = fq * (1.f / DD) - mean * mean;
        float inv = rsqrtf(var + 1e-5f);
        size_t grow = (size_t)(b * TT + (row < TT ? row : TT - 1)) * DD;
#pragma unroll
        for (int ntl = 0; ntl < 2; ++ntl) {
            int col = w * 32 + ntl * 16 + m16;
            float v = vv[ntl][r];
            if (row < TT) x[grow + col] = v;
            // stage xn(l+1) unconditionally (finite for clamped rows; garbage
            // rows feed only discarded GEMM output rows)
            xa[rl][col] = f2bf((v - mean) * inv * g1[col] + b1[col]);
        }
    }

    // ---------------- phase 3: QKV(l+1) from staged xn tile ----------------
    if (donext) {
        __syncthreads();   // (6) xn tile ready
#pragma unroll
        for (int fam = 0; fam < 3; ++fam) {
            const short* Wf = fam == 0 ? Wq : (fam == 1 ? Wk : Wv);
            const float* bsv = fam == 0 ? qbv : (fam == 1 ? kbv : vbv);
            const short* wfb = Wf + (size_t)(w * 2) * 4096 + lane * 8;
            f32x4 a3[2] = {};
#pragma unroll
            for (int kc = 0; kc < 8; ++kc) {
                s16x8 af = *(const s16x8*)&xa[m16][kc * 32 + quad * 8];
#pragma unroll
                for (int ntl = 0; ntl < 2; ++ntl) {
                    s16x8 bf = *(const s16x8*)(wfb + (size_t)ntl * 4096 + kc * 512);
                    a3[ntl] = __builtin_amdgcn_mfma_f32_16x16x32_bf16(af, bf, a3[ntl], 0, 0, 0);
                }
            }
            if (fam < 2) {
                short* outp = fam == 0 ? qho : kho;
#pragma unroll
                for (int ntl = 0; ntl < 2; ++ntl) {
                    int col = w * 32 + ntl * 16 + m16;
                    float bv = bsv[col];
                    int hh = col >> 5, dk = col & 31;
#pragma unroll
                    for (int r = 0; r < 4; ++r) {
                        int row = q0 + quad * 4 + r;
                        if (row < TT)
                            outp[((size_t)b * HH * KQP + row) * DKK
                                 + (size_t)hh * KHS + dk] = f2bf(a3[ntl][r] + bv);
                    }
                }
            } else {
#pragma unroll
                for (int ntl = 0; ntl < 2; ++ntl) {
                    int col = w * 32 + ntl * 16 + m16;
                    float bv = bsv[col];
                    int hh = col >> 5, dk = col & 31;
#pragma unroll
                    for (int r = 0; r < 4; ++r) {
                        int row = q0 + quad * 4 + r;
                        if (row < TT)
                            vto[(((size_t)(b * HH + hh)) * DKK + dk) * TP + row] =
                                f2bf(a3[ntl][r] + bv);
                    }
                }
            }
        }
    }
}

// ---------------- host ----------------
extern "C" void kernel_launch(void* const* d_in, const int* in_sizes, int n_in,
                              void* d_out, int out_size, void* d_ws, size_t ws_size,
                              hipStream_t stream)
{
    const float* node_feats = (const float*)d_in[0];
    const int*   adj        = (const int*)d_in[1];
    const float* dist       = (const float*)d_in[2];
    const float* eoh        = (const float*)d_in[3];
    const float* npw        = (const float*)d_in[4];
    const float* npb        = (const float*)d_in[5];
    const float* cls        = (const float*)d_in[6];
    const float* etw        = (const float*)d_in[7];
    const float* noedge     = (const float*)d_in[8];
    const float* degsc      = (const float*)d_in[9];
    const float* gamma      = (const float*)d_in[10];
    const float* v2n        = (const float*)d_in[11];
    const float* n2v        = (const float*)d_in[12];
    const float* vself      = (const float*)d_in[13];
    const float* ln1g = (const float*)d_in[14];
    const float* ln1b = (const float*)d_in[15];
    const float* qw   = (const float*)d_in[16];
    const float* qb   = (const float*)d_in[17];
    const float* kw   = (const float*)d_in[18];
    const float* kb   = (const float*)d_in[19];
    const float* vw   = (const float*)d_in[20];
    const float* vb   = (const float*)d_in[21];
    const float* ow   = (const float*)d_in[22];
    const float* ob   = (const float*)d_in[23];
    const float* ln2g = (const float*)d_in[24];
    const float* ln2b = (const float*)d_in[25];
    const float* f1w  = (const float*)d_in[26];
    const float* f1b  = (const float*)d_in[27];
    const float* f2w  = (const float*)d_in[28];
    const float* f2b  = (const float*)d_in[29];

    float* x  = (float*)d_out;   // (B,T,D) f32 residual stream
    char* ws = (char*)d_ws;
    size_t off = 0;
    unsigned short* bias = (unsigned short*)(ws + off); off += (size_t)BB * TT * GBP * 2;
    unsigned short* bpk  = (unsigned short*)(ws + off); off += NPK * 2;
    float* deg  = (float*)(ws + off); off += (size_t)BB * NN * 4;
    float* dmax = (float*)(ws + off); off += 64;
    short* xn16 = (short*)(ws + off); off += (size_t)MM * DD * 2;
    short* qhb[2]; short* khb[2]; short* vtb[2];
    qhb[0] = (short*)(ws + off); off += (size_t)BB * HH * KQP * DKK * 2;
    khb[0] = (short*)(ws + off); off += (size_t)BB * HH * KQP * DKK * 2;
    vtb[0] = (short*)(ws + off); off += (size_t)BB * HH * DKK * TP * 2;
    qhb[1] = (short*)(ws + off); off += (size_t)BB * HH * KQP * DKK * 2;
    khb[1] = (short*)(ws + off); off += (size_t)BB * HH * KQP * DKK * 2;
    vtb[1] = (short*)(ws + off); off += (size_t)BB * HH * DKK * TP * 2;
    short* wt2  = (short*)(ws + off); off += (size_t)36 * WSZ * 2;

    deg_kernel<<<(BB * NN) / 4, 256, 0, stream>>>(adj, deg);
    degmax_kernel<<<BB, 256, 0, stream>>>(deg, dmax);

    long long total = (long long)BB * TT * GBP;
    bias_kernel<<<(int)((total + 255) / 256), 256, 0, stream>>>(
        dist, eoh, adj, deg, dmax, etw, noedge, degsc, gamma, v2n, n2v, vself, bias);

    biaspk_kernel<<<(int)(NPK / 256), 256, 0, stream>>>(bias, bpk);

    nodeproj_ln_kernel<<<MM, 256, 0, stream>>>(node_feats, npw, npb, cls,
                                               ln1g, ln1b, x, xn16);

    wtrans_kernel<<<576, 256, 0, stream>>>(qw, kw, vw, ow, f1w, f2w, wt2);

    // layer-0 QKV from nodeproj's xn16
    dim3 gqkv(385, 3);
    gemm_qkv_kernel<<<gqkv, 256, 0, stream>>>(xn16, wt2,
                                              qb, kb, vb,
                                              qhb[0], khb[0], vtb[0]);

    for (int l = 0; l < LL; ++l) {
        size_t bo = (size_t)l * DD;
        int donext = (l + 1 < LL) ? 1 : 0;
        int ln = donext ? l + 1 : l;
        size_t bn = (size_t)ln * DD;
        int pi = l & 1, po = pi ^ 1;
        mega_kernel<<<392, 512, 0, stream>>>(
            qhb[pi], khb[pi], vtb[pi], bpk,
            wt2 + (size_t)(18 + l) * WSZ,
            wt2 + (size_t)(24 + l) * WSZ,
            wt2 + (size_t)(30 + l) * WSZ,
            ob + bo, ln2g + bo, ln2b + bo, f1b + bo, f2b + bo,
            x, ln1g + bn, ln1b + bn,
            wt2 + (size_t)(0 + ln) * WSZ,
            wt2 + (size_t)(6 + ln) * WSZ,
            wt2 + (size_t)(12 + ln) * WSZ,
            qb + bn, kb + bn, vb + bn,
            qhb[po], khb[po], vtb[po], donext);
    }
}

// Round 11
// 662.752 us; speedup vs baseline: 1.0617x; 1.0617x over previous
//
#include <hip/hip_runtime.h>
#include <math.h>

#define BB 8
#define NN 768
#define TT 769
#define DD 256
#define HH 8
#define DKK 32
#define FF 128
#define LL 6
#define MM 6152              // BB*TT
#define SCALE 0.17677669529663687f   // 1/sqrt(32)
#define TP 832               // vt row pitch (keys padded)
#define KQP 784              // q/k head-major row count (padded)
#define KHS (KQP * DKK)      // shorts per head slice (25088)
#define GBP 776              // bias global pitch (ushort)
#define HP 264               // LDS row pitch (shorts) for 16x256 tiles
#define WSZ 65536            // shorts per swizzled weight matrix
#define NPK ((size_t)BB * 49 * 13 * 1024)   // packed bias elements

typedef __attribute__((ext_vector_type(8))) short s16x8;
typedef __attribute__((ext_vector_type(8))) unsigned short u16x8;
typedef __attribute__((ext_vector_type(4))) float f32x4;

__device__ inline short f2bf(float x) {
    unsigned u = __float_as_uint(x);
    unsigned r = (u + 0x7FFFu + ((u >> 16) & 1u)) >> 16;   // RNE
    return (short)r;
}
__device__ inline float bf2f(unsigned short s) {
    return __uint_as_float(((unsigned)s) << 16);
}
__device__ inline float gelu_f(float x) {
    return 0.5f * x * (1.f + erff(x * 0.70710678118654752f));
}

// ---------------- degree ----------------
__global__ __launch_bounds__(256) void deg_kernel(const int* __restrict__ adj,
                                                  float* __restrict__ deg) {
    int row  = blockIdx.x * 4 + (threadIdx.x >> 6);
    int lane = threadIdx.x & 63;
    const int* p = adj + (size_t)row * NN;
    int s = 0;
#pragma unroll
    for (int i = 0; i < NN / 64; ++i) s += p[lane + 64 * i];
#pragma unroll
    for (int off = 32; off > 0; off >>= 1) s += __shfl_xor(s, off);
    if (lane == 0) deg[row] = (float)s;
}

__global__ __launch_bounds__(256) void degmax_kernel(const float* __restrict__ deg,
                                                     float* __restrict__ dmax) {
    __shared__ float red[256];
    int b = blockIdx.x, t = threadIdx.x;
    float m = 0.f;
    for (int i = t; i < NN; i += 256) m = fmaxf(m, deg[b * NN + i]);
    red[t] = m;
    __syncthreads();
    for (int s = 128; s > 0; s >>= 1) {
        if (t < s) red[t] = fmaxf(red[t], red[t + s]);
        __syncthreads();
    }
    if (t == 0) dmax[b] = red[0];
}

// ---------------- attention bias (B,TT,GBP) bf16 ----------------
__global__ __launch_bounds__(256) void bias_kernel(
    const float* __restrict__ dist, const float* __restrict__ eoh,
    const int* __restrict__ adj, const float* __restrict__ deg,
    const float* __restrict__ dmax, const float* __restrict__ etw,
    const float* __restrict__ noedge, const float* __restrict__ degsc,
    const float* __restrict__ gamma, const float* __restrict__ v2n,
    const float* __restrict__ n2v, const float* __restrict__ vself,
    unsigned short* __restrict__ bias)
{
    long long idx = (long long)blockIdx.x * 256 + threadIdx.x;
    const long long total = (long long)BB * TT * GBP;
    if (idx >= total) return;
    int b  = (int)(idx / ((long long)TT * GBP));
    int r  = (int)(idx % ((long long)TT * GBP));
    int qi = r / GBP, kj = r % GBP;
    float out;
    if (kj >= TT)                out = 0.f;
    else if (qi == 0 && kj == 0) out = vself[0];
    else if (qi == 0)            out = v2n[0];
    else if (kj == 0)            out = n2v[0];
    else {
        int i = qi - 1, j = kj - 1;
        size_t e = ((size_t)b * NN + i) * NN + j;
        float4 oh = *(const float4*)(eoh + 4 * e);
        float val = oh.x * etw[0] + oh.y * etw[1] + oh.z * etw[2] + oh.w * etw[3]
                    - gamma[0] * dist[e];
        if (adj[e] == 0) val += noedge[0];
        val += degsc[0] * (deg[b * NN + i] + deg[b * NN + j]) / (dmax[b] + 1e-6f);
        out = val;
    }
    bias[idx] = (unsigned short)f2bf(out);
}

// ---------------- bias repack: per-(qtile,chunk,lane) packed layout -----------------
__global__ __launch_bounds__(256) void biaspk_kernel(
    const unsigned short* __restrict__ bias, unsigned short* __restrict__ bpk)
{
    int idx = blockIdx.x * 256 + threadIdx.x;
    int jj   = idx & 7;
    int lane = (idx >> 3) & 63;
    int half = (idx >> 9) & 1;
    int c    = (idx >> 10) % 13;
    int qtb  = idx / (13 * 1024);
    int b = qtb / 49, qt = qtb - b * 49;
    int quad = lane >> 4, m16 = lane & 15;
    int j = half * 8 + jj, s = j >> 2, r = j & 3;
    int kj = c * 64 + s * 16 + m16; if (kj >= TT) kj = 0;
    int qi = qt * 16 + quad * 4 + r; if (qi >= TT) qi = TT - 1;
    bpk[idx] = bias[(size_t)(b * TT + qi) * GBP + kj];
}

// ---------------- node projection + cls + LN1(layer0) ----------------
__global__ __launch_bounds__(256) void nodeproj_ln_kernel(
    const float* __restrict__ nf, const float* __restrict__ w,
    const float* __restrict__ bsv, const float* __restrict__ cls,
    const float* __restrict__ g, const float* __restrict__ bvec,
    float* __restrict__ x, short* __restrict__ xn)
{
    __shared__ float sf[FF];
    __shared__ float red[256];
    int row = blockIdx.x, t = threadIdx.x;
    int b = row / TT, tr = row % TT;
    float y;
    if (tr == 0) {
        y = cls[t];
    } else {
        if (t < FF) sf[t] = nf[((size_t)b * NN + tr - 1) * FF + t];
        __syncthreads();
        y = bsv[t];
#pragma unroll 8
        for (int kk = 0; kk < FF; ++kk) y = fmaf(sf[kk], w[kk * DD + t], y);
    }
    x[(size_t)row * DD + t] = y;
    red[t] = y;
    __syncthreads();
    for (int s = 128; s > 0; s >>= 1) { if (t < s) red[t] += red[t + s]; __syncthreads(); }
    float mean = red[0] * (1.f / DD);
    __syncthreads();
    float d = y - mean;
    red[t] = d * d;
    __syncthreads();
    for (int s = 128; s > 0; s >>= 1) { if (t < s) red[t] += red[t + s]; __syncthreads(); }
    float var = red[0] * (1.f / DD);
    xn[(size_t)row * DD + t] = f2bf(d * rsqrtf(var + 1e-5f) * g[t] + bvec[t]);
}

// ---------------- weight swizzle: W[k][n] f32 -> frag-major bf16 ----------------
__global__ __launch_bounds__(256) void wtrans_kernel(
    const float* __restrict__ qw, const float* __restrict__ kw,
    const float* __restrict__ vw, const float* __restrict__ ow,
    const float* __restrict__ f1w, const float* __restrict__ f2w,
    short* __restrict__ wt2)
{
    int mi = blockIdx.x >> 4, kg = blockIdx.x & 15;
    int fam = mi / 6, l = mi % 6;
    const float* W;
    if      (fam == 0) W = qw;
    else if (fam == 1) W = kw;
    else if (fam == 2) W = vw;
    else if (fam == 3) W = ow;
    else if (fam == 4) W = f1w;
    else               W = f2w;
    W += (size_t)l * DD * DD;
    int n = threadIdx.x;
    short* out = wt2 + (size_t)mi * WSZ;
#pragma unroll
    for (int kk = 0; kk < 16; ++kk) {
        int k = kg * 16 + kk;
        float val = W[(size_t)k * DD + n];
        size_t idx = (size_t)(((n >> 4) * 8 + (k >> 5)) * 512
                   + (((k >> 3) & 3) * 16 + (n & 15)) * 8 + (k & 7));
        out[idx] = f2bf(val);
    }
}

// ---------------- fused QKV GEMM: XCD-pinned grid (392,3) ---------------------------
// bx -> b = bx&7, qt = bx>>3: batch b's tiles run on XCD b (same mapping as mega),
// so xn reads (written by mega on XCD b) and q/k/v writes (read by next mega on
// XCD b) are L2-local. Also removes the per-row /TT division.
__global__ __launch_bounds__(256) void gemm_qkv_kernel(
    const short* __restrict__ A, const short* __restrict__ wtl,
    const float* __restrict__ qb, const float* __restrict__ kb,
    const float* __restrict__ vb,
    short* __restrict__ qh, short* __restrict__ kh, short* __restrict__ vtb)
{
    int t = threadIdx.x;
    int w = t >> 6, lane = t & 63, quad = lane >> 4, m16 = lane & 15;
    int bx = blockIdx.x;
    int bb = bx & 7, qt = bx >> 3;
    int fam = blockIdx.y;
    const short* Wf = wtl + (size_t)fam * 6 * WSZ;
    const float* bsv = fam == 0 ? qb : (fam == 1 ? kb : vb);
    int tpa = qt * 16 + m16; if (tpa >= TT) tpa = TT - 1;
    const short* ap = A + (size_t)(bb * TT + tpa) * DD + quad * 8;
    const short* wbase = Wf + (size_t)(w * 4) * 4096 + lane * 8;
    f32x4 acc[4] = {};
#pragma unroll
    for (int kc = 0; kc < 8; ++kc) {
        s16x8 af = *(const s16x8*)(ap + kc * 32);
#pragma unroll
        for (int nt = 0; nt < 4; ++nt) {
            s16x8 bf = *(const s16x8*)(wbase + (size_t)nt * 4096 + kc * 512);
            acc[nt] = __builtin_amdgcn_mfma_f32_16x16x32_bf16(af, bf, acc[nt], 0, 0, 0);
        }
    }
    if (fam < 2) {
        short* outp = fam == 0 ? qh : kh;
#pragma unroll
        for (int r = 0; r < 4; ++r) {
            int tpos = qt * 16 + quad * 4 + r;
            if (tpos < TT) {
                size_t rb = ((size_t)bb * HH * KQP + tpos) * DKK;
#pragma unroll
                for (int nt = 0; nt < 4; ++nt) {
                    int col = w * 64 + nt * 16 + m16;
                    float bv = bsv[col];
                    int h = col >> 5, dk = col & 31;
                    outp[rb + (size_t)h * KHS + dk] = f2bf(acc[nt][r] + bv);
                }
            }
        }
    } else {
#pragma unroll
        for (int nt = 0; nt < 4; ++nt) {
            int col = w * 64 + nt * 16 + m16;
            float bv = bsv[col];
            int h = col >> 5, dk = col & 31;
#pragma unroll
            for (int r = 0; r < 4; ++r) {
                int tpos = qt * 16 + quad * 4 + r;
                if (tpos < TT)
                    vtb[(((size_t)(bb * HH + h)) * DKK + dk) * TP + tpos] =
                        f2bf(acc[nt][r] + bv);
            }
        }
    }
}

// ---------------- MEGA: attn + O-proj + LN2 + MLP + resid + LN1next -----------------
// grid (392); block 512 = 8 waves = 8 heads; 16 q-rows per block.
// XCD mapping: b = bx & 7 -> all 49 q-tiles of batch b on XCD b; per-XCD L2
// working set ~4.8MB ~= L2 -> K/V re-reads are L2 hits (R10: FETCH 39.7->16.8MB).
// R10 lesson: folding QKV(l+1) in-block REGRESSED (8-wave serial phase slower
// than the 1155-block dispatch it replaced) -- keep QKV as its own kernel.
__global__ __launch_bounds__(512) void mega_kernel(
    const short* __restrict__ q, const short* __restrict__ k,
    const short* __restrict__ vt, const unsigned short* __restrict__ bpk,
    const short* __restrict__ Wo, const short* __restrict__ W1,
    const short* __restrict__ W2,
    const float* __restrict__ ob, const float* __restrict__ g2,
    const float* __restrict__ b2, const float* __restrict__ f1b,
    const float* __restrict__ f2b, float* __restrict__ x,
    short* __restrict__ xn, const float* __restrict__ g1,
    const float* __restrict__ b1, int donext)
{
    __shared__ short Pb[8][16][72];        // 18.4KB per-wave P buffers
    __shared__ short xa[16][HP];           // 8.4KB attn-out tile
    __shared__ short xnl[16][HP];          // 8.4KB LN2-out tile
    __shared__ short hb[16][HP];           // 8.4KB gelu hidden tile
    __shared__ float redS[16][8], redQ[16][8];

    int t = threadIdx.x;
    int w = t >> 6, lane = t & 63;
    int quad = lane >> 4, m16 = lane & 15;
    int bx = blockIdx.x;
    int b = bx & 7;            // XCD-pinned batch
    int qt = bx >> 3;          // q-tile 0..48
    int h = w;
    int q0 = qt * 16;
    size_t qtb13 = (size_t)(b * 49 + qt) * 13;

    int qrow = q0 + m16;
    int qc = qrow < TT ? qrow : TT - 1;
    const short* qbase = q + (size_t)(b * HH + h) * KHS;
    s16x8 qa = *(const s16x8*)(qbase + (size_t)qc * DKK + quad * 8);

    const short* kbase = k + (size_t)(b * HH + h) * KHS;
    const short* vbase = vt + (((size_t)(b * HH + h)) * DKK) * TP;

    s16x8 kfA[4], kfB[4], vfA[4], vfB[4];
    u16x8 bbA0, bbA1, bbB0, bbB1;
    f32x4 sacc[4];
    f32x4 o0 = {0.f, 0.f, 0.f, 0.f};
    f32x4 o1 = {0.f, 0.f, 0.f, 0.f};
    float ls[4] = {0.f, 0.f, 0.f, 0.f};

#define LOADK_(DST, CC)                                                         \
    {                                                                           \
        _Pragma("unroll") for (int s = 0; s < 4; ++s) {                         \
            int kr = (CC) * 64 + s * 16 + m16;                                  \
            int kcl = kr < TT ? kr : TT - 1;                                    \
            DST[s] = *(const s16x8*)(kbase + (size_t)kcl * DKK + quad * 8);     \
        }                                                                       \
    }
#define LOADV_(DST, CC)                                                         \
    {                                                                           \
        int jn = (CC) * 64;                                                     \
        DST[0] = *(const s16x8*)(vbase + (size_t)m16 * TP + jn + quad * 8);     \
        DST[1] = *(const s16x8*)(vbase + (size_t)m16 * TP + jn + 32 + quad * 8);\
        DST[2] = *(const s16x8*)(vbase + (size_t)(16 + m16) * TP + jn + quad * 8);\
        DST[3] = *(const s16x8*)(vbase + (size_t)(16 + m16) * TP + jn + 32 + quad * 8);\
    }
#define LOADB_(D0, D1, CC)                                                      \
    {                                                                           \
        const unsigned short* bp_ = bpk + ((qtb13 + (CC)) << 10);               \
        D0 = *(const u16x8*)(bp_ + (lane << 3));                                \
        D1 = *(const u16x8*)(bp_ + 512 + (lane << 3));                         \
    }
#define STEP_(C, KPRE, KUSE, VUSE, VPRE, BU0, BU1, BP0, BP1, PK, PV, PBF, DOQK) \
    {                                                                           \
        if (PK)  LOADK_(KPRE, (C) + 2);                                         \
        if (PV)  LOADV_(VPRE, (C) + 1);                                         \
        if (PBF) LOADB_(BP0, BP1, (C) + 1);                                     \
        int j0 = (C) * 64;                                                      \
        _Pragma("unroll") for (int s = 0; s < 4; ++s) {                         \
            int key = j0 + s * 16 + m16;                                        \
            int kv = key < TT;                                                  \
            _Pragma("unroll") for (int r = 0; r < 4; ++r) {                     \
                int j = s * 4 + r;                                              \
                float bv = bf2f(j < 8 ? (unsigned short)BU0[j]                  \
                                      : (unsigned short)BU1[j - 8]);            \
                float sval = kv ? fmaf(sacc[s][r], SCALE, bv) : -1e30f;         \
                float p = __expf(sval - 8.0f);                                  \
                ls[r] += p;                                                     \
                Pb[w][quad * 4 + r][s * 16 + m16] = f2bf(p);                    \
            }                                                                   \
        }                                                                       \
        if (DOQK) {                                                             \
            f32x4 z = {0.f, 0.f, 0.f, 0.f};                                     \
            _Pragma("unroll") for (int s = 0; s < 4; ++s)                       \
                sacc[s] = __builtin_amdgcn_mfma_f32_16x16x32_bf16(qa, KUSE[s], z, 0, 0, 0); \
        }                                                                       \
        s16x8 pa0 = *(const s16x8*)&Pb[w][m16][quad * 8];                       \
        s16x8 pa1 = *(const s16x8*)&Pb[w][m16][32 + quad * 8];                  \
        o0 = __builtin_amdgcn_mfma_f32_16x16x32_bf16(pa0, VUSE[0], o0, 0, 0, 0);\
        o0 = __builtin_amdgcn_mfma_f32_16x16x32_bf16(pa1, VUSE[1], o0, 0, 0, 0);\
        o1 = __builtin_amdgcn_mfma_f32_16x16x32_bf16(pa0, VUSE[2], o1, 0, 0, 0);\
        o1 = __builtin_amdgcn_mfma_f32_16x16x32_bf16(pa1, VUSE[3], o1, 0, 0, 0);\
    }

    // prologue
    LOADK_(kfA, 0);
    LOADK_(kfB, 1);
    LOADV_(vfA, 0);
    LOADB_(bbA0, bbA1, 0);
    {
        f32x4 z = {0.f, 0.f, 0.f, 0.f};
#pragma unroll
        for (int s = 0; s < 4; ++s)
            sacc[s] = __builtin_amdgcn_mfma_f32_16x16x32_bf16(qa, kfA[s], z, 0, 0, 0);
    }

    // steady state: c = 0..9, rolled 2 steps per iteration (small hot loop)
    for (int cc = 0; cc < 5; ++cc) {
        STEP_(2 * cc,     kfA, kfB, vfA, vfB, bbA0, bbA1, bbB0, bbB1, 1, 1, 1, 1)
        STEP_(2 * cc + 1, kfB, kfA, vfB, vfA, bbB0, bbB1, bbA0, bbA1, 1, 1, 1, 1)
    }
    STEP_(10, kfA, kfB, vfA, vfB, bbA0, bbA1, bbB0, bbB1, 1, 1, 1, 1)
    STEP_(11, kfB, kfA, vfB, vfA, bbB0, bbB1, bbA0, bbA1, 0, 1, 1, 1)
    STEP_(12, kfA, kfB, vfA, vfB, bbA0, bbA1, bbB0, bbB1, 0, 0, 0, 0)

#undef STEP_
#undef LOADB_
#undef LOADV_
#undef LOADK_

    // attn epilogue -> LDS xa
#pragma unroll
    for (int r = 0; r < 4; ++r) {
        float l = ls[r];
#pragma unroll
        for (int off = 1; off < 16; off <<= 1) l += __shfl_xor(l, off);
        float inv = 1.f / l;
        int rl = quad * 4 + r;
        xa[rl][h * DKK + m16]      = f2bf(o0[r] * inv);
        xa[rl][h * DKK + 16 + m16] = f2bf(o1[r] * inv);
    }
    __syncthreads();   // (1) xa complete

    // ---------------- phase 2: O-proj + resid(reg) + LN2 ----------------
    const short* wob = Wo + (size_t)(w * 2) * 4096 + lane * 8;
    f32x4 acco[2] = {};
#pragma unroll
    for (int kc = 0; kc < 8; ++kc) {
        s16x8 af = *(const s16x8*)&xa[m16][kc * 32 + quad * 8];
#pragma unroll
        for (int ntl = 0; ntl < 2; ++ntl) {
            s16x8 bf = *(const s16x8*)(wob + (size_t)ntl * 4096 + kc * 512);
            acco[ntl] = __builtin_amdgcn_mfma_f32_16x16x32_bf16(af, bf, acco[ntl], 0, 0, 0);
        }
    }
    float vv[2][4], sr[4], q2[4];
#pragma unroll
    for (int r = 0; r < 4; ++r) { sr[r] = 0.f; q2[r] = 0.f; }
#pragma unroll
    for (int ntl = 0; ntl < 2; ++ntl) {
        int col = w * 32 + ntl * 16 + m16;
        float bv = ob[col];
#pragma unroll
        for (int r = 0; r < 4; ++r) {
            int row = q0 + quad * 4 + r; if (row >= TT) row = TT - 1;
            float v = acco[ntl][r] + bv + x[((size_t)(b * TT + row)) * DD + col];
            vv[ntl][r] = v; sr[r] += v; q2[r] += v * v;
        }
    }
#pragma unroll
    for (int r = 0; r < 4; ++r)
#pragma unroll
        for (int off = 1; off < 16; off <<= 1) {
            sr[r] += __shfl_xor(sr[r], off);
            q2[r] += __shfl_xor(q2[r], off);
        }
    if (m16 == 0) {
#pragma unroll
        for (int r = 0; r < 4; ++r) {
            redS[quad * 4 + r][w] = sr[r];
            redQ[quad * 4 + r][w] = q2[r];
        }
    }
    __syncthreads();   // (2) LN2 partials ready

#pragma unroll
    for (int r = 0; r < 4; ++r) {
        int rl = quad * 4 + r;
        float fs = 0.f, fq = 0.f;
#pragma unroll
        for (int j = 0; j < 8; ++j) { fs += redS[rl][j]; fq += redQ[rl][j]; }
        float mean = fs * (1.f / DD);
        float var = fq * (1.f / DD) - mean * mean;
        float inv = rsqrtf(var + 1e-5f);
#pragma unroll
        for (int ntl = 0; ntl < 2; ++ntl) {
            int col = w * 32 + ntl * 16 + m16;
            xnl[rl][col] = f2bf((vv[ntl][r] - mean) * inv * g2[col] + b2[col]);
        }
    }
    __syncthreads();   // (3) xnl complete

    // ---------------- FC1 + GELU -> hb ----------------
    const short* w1b = W1 + (size_t)(w * 2) * 4096 + lane * 8;
    f32x4 acc1[2] = {};
#pragma unroll
    for (int kc = 0; kc < 8; ++kc) {
        s16x8 af = *(const s16x8*)&xnl[m16][kc * 32 + quad * 8];
#pragma unroll
        for (int ntl = 0; ntl < 2; ++ntl) {
            s16x8 bf = *(const s16x8*)(w1b + (size_t)ntl * 4096 + kc * 512);
            acc1[ntl] = __builtin_amdgcn_mfma_f32_16x16x32_bf16(af, bf, acc1[ntl], 0, 0, 0);
        }
    }
#pragma unroll
    for (int ntl = 0; ntl < 2; ++ntl) {
        int col = w * 32 + ntl * 16 + m16;
        float fb = f1b[col];
#pragma unroll
        for (int r = 0; r < 4; ++r)
            hb[quad * 4 + r][col] = f2bf(gelu_f(acc1[ntl][r] + fb));
    }
    __syncthreads();   // (4) hidden complete

    // ---------------- FC2 + reg-resid + LN1next ----------------
    const short* w2b = W2 + (size_t)(w * 2) * 4096 + lane * 8;
    f32x4 acc2[2] = {};
#pragma unroll
    for (int kc = 0; kc < 8; ++kc) {
        s16x8 af = *(const s16x8*)&hb[m16][kc * 32 + quad * 8];
#pragma unroll
        for (int ntl = 0; ntl < 2; ++ntl) {
            s16x8 bf = *(const s16x8*)(w2b + (size_t)ntl * 4096 + kc * 512);
            acc2[ntl] = __builtin_amdgcn_mfma_f32_16x16x32_bf16(af, bf, acc2[ntl], 0, 0, 0);
        }
    }
#pragma unroll
    for (int r = 0; r < 4; ++r) { sr[r] = 0.f; q2[r] = 0.f; }
#pragma unroll
    for (int ntl = 0; ntl < 2; ++ntl) {
        int col = w * 32 + ntl * 16 + m16;
        float bv = f2b[col];
#pragma unroll
        for (int r = 0; r < 4; ++r) {
            float v = acc2[ntl][r] + bv + vv[ntl][r];   // resid = post-attn x (regs)
            vv[ntl][r] = v; sr[r] += v; q2[r] += v * v;
        }
    }
#pragma unroll
    for (int r = 0; r < 4; ++r)
#pragma unroll
        for (int off = 1; off < 16; off <<= 1) {
            sr[r] += __shfl_xor(sr[r], off);
            q2[r] += __shfl_xor(q2[r], off);
        }
    if (m16 == 0) {
#pragma unroll
        for (int r = 0; r < 4; ++r) {
            redS[quad * 4 + r][w] = sr[r];
            redQ[quad * 4 + r][w] = q2[r];
        }
    }
    __syncthreads();   // (5) LN1 partials ready

#pragma unroll
    for (int r = 0; r < 4; ++r) {
        int rl = quad * 4 + r;
        int row = q0 + rl;
        float fs = 0.f, fq = 0.f;
#pragma unroll
        for (int j = 0; j < 8; ++j) { fs += redS[rl][j]; fq += redQ[rl][j]; }
        float mean = fs * (1.f / DD);
        float var = fq * (1.f / DD) - mean * mean;
        float inv = rsqrtf(var + 1e-5f);
        if (row < TT) {
            size_t grow = (size_t)(b * TT + row) * DD;
#pragma unroll
            for (int ntl = 0; ntl < 2; ++ntl) {
                int col = w * 32 + ntl * 16 + m16;
                float v = vv[ntl][r];
                x[grow + col] = v;
                if (donext)
                    xn[grow + col] = f2bf((v - mean) * inv * g1[col] + b1[col]);
            }
        }
    }
}

// ---------------- host ----------------
extern "C" void kernel_launch(void* const* d_in, const int* in_sizes, int n_in,
                              void* d_out, int out_size, void* d_ws, size_t ws_size,
                              hipStream_t stream)
{
    const float* node_feats = (const float*)d_in[0];
    const int*   adj        = (const int*)d_in[1];
    const float* dist       = (const float*)d_in[2];
    const float* eoh        = (const float*)d_in[3];
    const float* npw        = (const float*)d_in[4];
    const float* npb        = (const float*)d_in[5];
    const float* cls        = (const float*)d_in[6];
    const float* etw        = (const float*)d_in[7];
    const float* noedge     = (const float*)d_in[8];
    const float* degsc      = (const float*)d_in[9];
    const float* gamma      = (const float*)d_in[10];
    const float* v2n        = (const float*)d_in[11];
    const float* n2v        = (const float*)d_in[12];
    const float* vself      = (const float*)d_in[13];
    const float* ln1g = (const float*)d_in[14];
    const float* ln1b = (const float*)d_in[15];
    const float* qw   = (const float*)d_in[16];
    const float* qb   = (const float*)d_in[17];
    const float* kw   = (const float*)d_in[18];
    const float* kb   = (const float*)d_in[19];
    const float* vw   = (const float*)d_in[20];
    const float* vb   = (const float*)d_in[21];
    const float* ow   = (const float*)d_in[22];
    const float* ob   = (const float*)d_in[23];
    const float* ln2g = (const float*)d_in[24];
    const float* ln2b = (const float*)d_in[25];
    const float* f1w  = (const float*)d_in[26];
    const float* f1b  = (const float*)d_in[27];
    const float* f2w  = (const float*)d_in[28];
    const float* f2b  = (const float*)d_in[29];

    float* x  = (float*)d_out;   // (B,T,D) f32 residual stream
    char* ws = (char*)d_ws;
    size_t off = 0;
    unsigned short* bias = (unsigned short*)(ws + off); off += (size_t)BB * TT * GBP * 2;
    unsigned short* bpk  = (unsigned short*)(ws + off); off += NPK * 2;
    float* deg  = (float*)(ws + off); off += (size_t)BB * NN * 4;
    float* dmax = (float*)(ws + off); off += 64;
    short* xn16 = (short*)(ws + off); off += (size_t)MM * DD * 2;
    short* qhb  = (short*)(ws + off); off += (size_t)BB * HH * KQP * DKK * 2;
    short* khb  = (short*)(ws + off); off += (size_t)BB * HH * KQP * DKK * 2;
    short* vtb  = (short*)(ws + off); off += (size_t)BB * HH * DKK * TP * 2;
    short* wt2  = (short*)(ws + off); off += (size_t)36 * WSZ * 2;

    deg_kernel<<<(BB * NN) / 4, 256, 0, stream>>>(adj, deg);
    degmax_kernel<<<BB, 256, 0, stream>>>(deg, dmax);

    long long total = (long long)BB * TT * GBP;
    bias_kernel<<<(int)((total + 255) / 256), 256, 0, stream>>>(
        dist, eoh, adj, deg, dmax, etw, noedge, degsc, gamma, v2n, n2v, vself, bias);

    biaspk_kernel<<<(int)(NPK / 256), 256, 0, stream>>>(bias, bpk);

    nodeproj_ln_kernel<<<MM, 256, 0, stream>>>(node_feats, npw, npb, cls,
                                               ln1g, ln1b, x, xn16);

    wtrans_kernel<<<576, 256, 0, stream>>>(qw, kw, vw, ow, f1w, f2w, wt2);

    dim3 gqkv(392, 3);
    gemm_qkv_kernel<<<gqkv, 256, 0, stream>>>(xn16, wt2, qb, kb, vb,
                                              qhb, khb, vtb);

    for (int l = 0; l < LL; ++l) {
        size_t bo = (size_t)l * DD;
        int donext = (l + 1 < LL) ? 1 : 0;
        size_t bn = (size_t)(l + 1 < LL ? l + 1 : 0) * DD;
        mega_kernel<<<392, 512, 0, stream>>>(
            qhb, khb, vtb, bpk,
            wt2 + (size_t)(18 + l) * WSZ,
            wt2 + (size_t)(24 + l) * WSZ,
            wt2 + (size_t)(30 + l) * WSZ,
            ob + bo, ln2g + bo, ln2b + bo, f1b + bo, f2b + bo,
            x, xn16, ln1g + bn, ln1b + bn, donext);
        if (donext)
            gemm_qkv_kernel<<<gqkv, 256, 0, stream>>>(
                xn16, wt2 + (size_t)(l + 1) * WSZ,
                qb + bn, kb + bn, vb + bn, qhb, khb, vtb);
    }
}